// Round 11
// baseline (1767.970 us; speedup 1.0000x reference)
//
#include <hip/hip_runtime.h>
#include <hip/hip_fp16.h>

typedef _Float16 f16;
typedef _Float16 f16x8 __attribute__((ext_vector_type(8)));
typedef float f32x4 __attribute__((ext_vector_type(4)));
typedef int int4v __attribute__((ext_vector_type(4)));

#define BM 128
#define BN 128
#define NBUF 3
#define BUFSZ 16384              // A 8KB + B 8KB (int8, K-tile = 64)

typedef const __attribute__((address_space(1))) unsigned int* gas_ptr;
typedef __attribute__((address_space(3))) unsigned int* las_ptr;

__device__ __forceinline__ void gload_lds16(const void* g, void* l) {
    __builtin_amdgcn_global_load_lds((gas_ptr)g, (las_ptr)l, 16, 0, 0);
}

// ---------------------------------------------------------------------------
// Pre-pass 1: per-row int8 quantization of xs = x/smooth.
// Outputs: Aq[M][K] int8, sx[M] f32, U[M][32] f16 (per-group sums of xs)
// ---------------------------------------------------------------------------
__global__ __launch_bounds__(256) void quantx_kernel(
    const float* __restrict__ x, const float* __restrict__ smooth,
    char* __restrict__ Aq, float* __restrict__ sx, f16* __restrict__ U,
    int M, int K)
{
    const int row = blockIdx.x * 4 + (threadIdx.x >> 6);
    const int lane = threadIdx.x & 63;
    if (row >= M) return;

    f32x4 xsv[16];
    float amax = 0.f;
#pragma unroll
    for (int j = 0; j < 16; ++j) {
        const int k = j * 256 + lane * 4;
        const f32x4 xv = *(const f32x4*)(x + (size_t)row * K + k);
        const f32x4 sv = *(const f32x4*)(smooth + k);
        f32x4 r;
#pragma unroll
        for (int e = 0; e < 4; ++e) {
            r[e] = xv[e] / sv[e];
            amax = fmaxf(amax, fabsf(r[e]));
        }
        xsv[j] = r;
    }
#pragma unroll
    for (int off = 1; off < 64; off <<= 1)
        amax = fmaxf(amax, __shfl_xor(amax, off));
    const float sxr = fmaxf(amax, 1e-20f) / 127.f;
    const float inv = 127.f / fmaxf(amax, 1e-20f);
    if (lane == 0) sx[row] = sxr;

    int* aq32 = (int*)(Aq + (size_t)row * K);
#pragma unroll
    for (int j = 0; j < 16; ++j) {
        unsigned int pk = 0;
        float s4 = 0.f;
#pragma unroll
        for (int e = 0; e < 4; ++e) {
            const float v = xsv[j][e];
            s4 += v;
            int qi = (int)__builtin_rintf(v * inv);
            qi = qi > 127 ? 127 : (qi < -127 ? -127 : qi);
            pk |= ((unsigned int)(qi & 255)) << (8 * e);
        }
        aq32[j * 64 + lane] = (int)pk;
#pragma unroll
        for (int off = 1; off < 32; off <<= 1)
            s4 += __shfl_xor(s4, off);
        if ((lane & 31) == 0)
            U[(size_t)row * 32 + 2 * j + (lane >> 5)] = (f16)s4;
    }
}

// ---------------------------------------------------------------------------
// Pre-pass 2: unpack int32-per-byte nibbles -> Wq[N][K] int8 (q-8, exact).
// ---------------------------------------------------------------------------
__global__ __launch_bounds__(256) void repackw_kernel(
    const int* __restrict__ packed, char* __restrict__ Wq, int total8)
{
    const int i = blockIdx.x * 256 + threadIdx.x;
    if (i >= total8) return;
    const int4v p0 = *(const int4v*)(packed + i * 8);
    const int4v p1 = *(const int4v*)(packed + i * 8 + 4);
    int4v o;
#pragma unroll
    for (int w = 0; w < 4; ++w) {
        const int a = (w < 2) ? p0[2 * w] : p1[2 * (w - 2)];
        const int b = (w < 2) ? p0[2 * w + 1] : p1[2 * (w - 2) + 1];
        const int l0 = ((a & 15) - 8) & 255, h0 = (((a >> 4) & 15) - 8) & 255;
        const int l1 = ((b & 15) - 8) & 255, h1 = (((b >> 4) & 15) - 8) & 255;
        o[w] = l0 | (h0 << 8) | (l1 << 16) | (h1 << 24);
    }
    *(int4v*)(Wq + (size_t)i * 16) = o;
}

// ---------------------------------------------------------------------------
// Pre-pass 3: Vneg[N][32] f16 = -wscale[g][n] * wzero[g][n]
// ---------------------------------------------------------------------------
__global__ __launch_bounds__(256) void vneg_kernel(
    const float* __restrict__ wscale, const float* __restrict__ wzero,
    f16* __restrict__ Vneg, int N)
{
    const int i = blockIdx.x * 256 + threadIdx.x;
    if (i >= N * 32) return;
    const int n = i >> 5;
    const int g = i & 31;
    Vneg[i] = (f16)(-wscale[(size_t)g * N + n] * wzero[(size_t)g * N + n]);
}

// ---------------------------------------------------------------------------
// GEMM (i8 MFMA), group-major + occupancy: 128x128 tile, 4 waves (2x2),
// NBUF=3 (48KB) -> 3 blocks/CU. Per K-128 group g:
//   stage tile 2g+2 -> free buf; ds_read 16 frags (tiles 2g,2g+1);
//   lgkmcnt(0)+sched_barrier+s_barrier; stage tile 2g+3 -> retired d0 buf;
//   16 chained MFMA pairs (i32 C through the pair => ONE fixup per frag
//   per K-128, halving fixup VALU vs r10); vmcnt(0)+barrier at group end.
// r9/r10-proven staging geometry / XOR swizzle (0 conflicts) / epilogue.
// ---------------------------------------------------------------------------
__global__ __launch_bounds__(256, 3) void gemm_kernel(
    const char* __restrict__ Aq,       // [M][K] int8
    const char* __restrict__ Wq,       // [N][K] int8
    const float* __restrict__ wscale,  // [32][N] f32
    const float* __restrict__ sx,      // [M] f32
    const f16* __restrict__ U,         // [M][32] f16
    const f16* __restrict__ Vneg,      // [N][32] f16
    const float* __restrict__ bias,    // [N]
    float* __restrict__ C,             // [M][N] f32
    int M, int N, int K)
{
    __shared__ char lds[NBUF * BUFSZ];   // 48 KiB

    const int t = threadIdx.x;
    const int lane = t & 63;
    const int wid = t >> 6;
    const int wr = wid >> 1;          // 0..1 (M half)
    const int wc = wid & 1;           // 0..1 (N half)
    const int fr = lane & 15;
    const int fq = lane >> 4;

    const int nbm = M / BM;           // 64
    const int nbn = N / BN;           // 86
    const int nwg = nbm * nbn;        // 5504, %8 == 0
    const int bid = (int)blockIdx.x;
    const int cpx = nwg >> 3;
    const int wg = ((nwg & 7) == 0) ? ((bid & 7) * cpx + (bid >> 3)) : bid;
    const int bm = wg % nbm;          // bm-major: consecutive wg share B panel
    const int bn = wg / nbm;
    const size_t m0 = (size_t)bm * BM;
    const size_t n0 = (size_t)bn * BN;

    // ---- staging geometry (256 threads, 4KB per gload; r9-verified map) ----
    const int scv = (t & 7) ^ ((t >> 3) & 7);
    const int rbase = 2 * (t >> 3) + (scv >> 2);   // 0..63
    const int kb = (scv & 3) * 16;                 // byte offset in 64B row
    const char* gAq = Aq + (m0 + rbase) * (size_t)K + kb;
    const char* gWq = Wq + (n0 + rbase) * (size_t)K + kb;

#define STAGE_AB(sb, Tst) do { char* _d = lds + (sb) + t * 16; \
    gload_lds16(gAq + (size_t)(Tst) * 64, _d); \
    gload_lds16(gAq + (size_t)64 * K + (size_t)(Tst) * 64, _d + 4096); \
    gload_lds16(gWq + (size_t)(Tst) * 64, _d + 8192); \
    gload_lds16(gWq + (size_t)64 * K + (size_t)(Tst) * 64, _d + 12288); } while (0)

    // ---- ds_read lane constants (r9-proven swizzle) ----
    const int aswz = ((((fr & 1) << 2) | fq) ^ ((fr >> 1) & 7)) << 4;
    const int aBase = wr * 4096 + ((fr >> 1) << 7) + aswz;
    const int bBase = 8192 + wc * 4096 + ((fr >> 1) << 7) + aswz;

#define LDA(db, m) (*(const int4v*)(lds + (db) + aBase + (m) * 1024))
#define LDB(db, n) (*(const int4v*)(lds + (db) + bBase + (n) * 1024))

    f32x4 accf[4][4];
#pragma unroll
    for (int m = 0; m < 4; ++m)
#pragma unroll
        for (int n = 0; n < 4; ++n)
            accf[m][n] = {0.f, 0.f, 0.f, 0.f};

    const int4v kz = {0, 0, 0, 0};
    const int NT = K >> 6;            // 64 K-64 tiles
    const int NG = K >> 7;            // 32 K-128 groups

    // ---- prologue: stage tiles 0,1 (bufs 0,1); load group-0 scales ----
    STAGE_AB(0, 0);
    STAGE_AB(BUFSZ, 1);
    float sgc[4], sgn[4];
#pragma unroll
    for (int n = 0; n < 4; ++n)
        sgc[n] = wscale[n0 + wc * 64 + n * 16 + fr];
    asm volatile("s_waitcnt vmcnt(0)" ::: "memory");
    __builtin_amdgcn_s_barrier();

#pragma unroll 1
    for (int g = 0; g < NG; ++g) {
        const int T0 = 2 * g;
        const int db0 = (T0 % 3) * BUFSZ;
        const int db1 = ((T0 + 1) % 3) * BUFSZ;
        const int fb  = ((T0 + 2) % 3) * BUFSZ;

        // ---- stage tile 2g+2 into the free buffer ----
        if (T0 + 2 < NT) STAGE_AB(fb, T0 + 2);

        // ---- read all 16 fragments of the group's tile pair ----
        int4v a0[4], a1[4], b0[4], b1[4];
#pragma unroll
        for (int m = 0; m < 4; ++m) { a0[m] = LDA(db0, m); a1[m] = LDA(db1, m); }
#pragma unroll
        for (int n = 0; n < 4; ++n) { b0[n] = LDB(db0, n); b1[n] = LDB(db1, n); }
        asm volatile("s_waitcnt lgkmcnt(0)" ::: "memory");
        __builtin_amdgcn_sched_barrier(0);
        __builtin_amdgcn_s_barrier();          // all waves done reading d0/d1

        // ---- stage tile 2g+3 into the just-retired d0 buffer ----
        if (T0 + 3 < NT) STAGE_AB(db0, T0 + 3);

        // ---- prefetch next group's scales ----
        if (g + 1 < NG) {
#pragma unroll
            for (int n = 0; n < 4; ++n)
                sgn[n] = wscale[(size_t)(g + 1) * N + n0 + wc * 64 + n * 16 + fr];
        }

        // ---- 16 chained MFMA pairs, one fixup per frag per K-128 ----
        __builtin_amdgcn_s_setprio(1);
#pragma unroll
        for (int m = 0; m < 4; ++m)
#pragma unroll
            for (int n = 0; n < 4; ++n) {
                int4v tv = __builtin_amdgcn_mfma_i32_16x16x64_i8(
                    a0[m], b0[n], kz, 0, 0, 0);
                tv = __builtin_amdgcn_mfma_i32_16x16x64_i8(
                    a1[m], b1[n], tv, 0, 0, 0);
#pragma unroll
                for (int e = 0; e < 4; ++e)
                    accf[m][n][e] += sgc[n] * (float)tv[e];
            }
        __builtin_amdgcn_s_setprio(0);

        if (g + 1 < NG) {
#pragma unroll
            for (int n = 0; n < 4; ++n) sgc[n] = sgn[n];
        }

        // ---- group-boundary sync ----
        asm volatile("s_waitcnt vmcnt(0)" ::: "memory");
        __builtin_amdgcn_s_barrier();
    }

    // ---- epilogue 1: scale by per-row sx ----
#pragma unroll
    for (int m = 0; m < 4; ++m) {
        const f32x4 sxv = *(const f32x4*)(sx + m0 + wr * 64 + m * 16 + fq * 4);
#pragma unroll
        for (int n = 0; n < 4; ++n)
#pragma unroll
            for (int e = 0; e < 4; ++e)
                accf[m][n][e] *= sxv[e];
    }

    // ---- epilogue 2: rank-32 zero-point correction via f16 MFMA ----
    {
        f16x8 uf[4], vf[4];
#pragma unroll
        for (int m = 0; m < 4; ++m)
            uf[m] = *(const f16x8*)(U + (m0 + wr * 64 + m * 16 + fr) * 32 + fq * 8);
#pragma unroll
        for (int n = 0; n < 4; ++n)
            vf[n] = *(const f16x8*)(Vneg + (n0 + wc * 64 + n * 16 + fr) * 32 + fq * 8);
#pragma unroll
        for (int m = 0; m < 4; ++m)
#pragma unroll
            for (int n = 0; n < 4; ++n)
                accf[m][n] = __builtin_amdgcn_mfma_f32_16x16x32_f16(
                    uf[m], vf[n], accf[m][n], 0, 0, 0);
    }

    // ---- epilogue 3: + bias, f32 scatter stores (static indices) ----
#pragma unroll
    for (int n = 0; n < 4; ++n) {
        const size_t gcol = n0 + wc * 64 + n * 16 + fr;
        const float bv = bias[gcol];
#pragma unroll
        for (int am = 0; am < 4; ++am) {
            const size_t grow = m0 + wr * 64 + am * 16 + fq * 4;
#pragma unroll
            for (int r = 0; r < 4; ++r)
                C[(grow + r) * N + gcol] = accf[am][n][r] + bv;
        }
    }
}

extern "C" void kernel_launch(void* const* d_in, const int* in_sizes, int n_in,
                              void* d_out, int out_size, void* d_ws, size_t ws_size,
                              hipStream_t stream) {
    const float* x      = (const float*)d_in[0];
    const int* packed   = (const int*)d_in[1];
    const float* wscale = (const float*)d_in[2];
    const float* wzero  = (const float*)d_in[3];
    const float* smooth = (const float*)d_in[4];
    const float* bias   = (const float*)d_in[5];
    float* out = (float*)d_out;

    const int K = in_sizes[4];             // 4096
    const int N = in_sizes[5];             // 11008
    const int M = in_sizes[0] / K;         // 8192
    const size_t MK = (size_t)M * K;
    const size_t NK = (size_t)N * K;

    char* Aq  = (char*)d_ws;
    char* Wq  = Aq + MK;
    f16* U    = (f16*)(Wq + NK);
    f16* Vneg = U + (size_t)M * 32;
    float* sxp = (float*)(Vneg + (size_t)N * 32);

    quantx_kernel<<<(M + 3) / 4, 256, 0, stream>>>(x, smooth, Aq, sxp, U, M, K);
    const int total8 = (int)(NK / 16);
    repackw_kernel<<<(total8 + 255) / 256, 256, 0, stream>>>(packed, Wq, total8);
    vneg_kernel<<<(N * 32 + 255) / 256, 256, 0, stream>>>(wscale, wzero, Vneg, N);

    const int grid_gemm = (M / BM) * (N / BN);
    gemm_kernel<<<grid_gemm, 256, 0, stream>>>(
        Aq, Wq, wscale, sxp, U, Vneg, bias, out, M, N, K);
}

// Round 12
// 867.620 us; speedup vs baseline: 2.0377x; 2.0377x over previous
//
#include <hip/hip_runtime.h>
#include <hip/hip_fp16.h>

typedef _Float16 f16;
typedef _Float16 f16x8 __attribute__((ext_vector_type(8)));
typedef float f32x4 __attribute__((ext_vector_type(4)));
typedef int int4v __attribute__((ext_vector_type(4)));

#define BM 256
#define BN 256
// BK=64 f16; LDS: A 2x32KB at 0, B 2x32KB at 65536.

typedef const __attribute__((address_space(1))) unsigned int* gas_ptr;
typedef __attribute__((address_space(3))) unsigned int* las_ptr;

__device__ __forceinline__ void gload_lds16(const void* g, void* l) {
    __builtin_amdgcn_global_load_lds((gas_ptr)g, (las_ptr)l, 16, 0, 0);
}

// ---------------------------------------------------------------------------
// Pre-pass 1: xs[M,K] = fp16(x / smooth)
// ---------------------------------------------------------------------------
__global__ __launch_bounds__(256) void smooth_kernel(
    const float* __restrict__ x, const float* __restrict__ smooth,
    f16* __restrict__ xs, int MK, int K)
{
    const int t = blockIdx.x * 256 + threadIdx.x;
    const int i0 = t * 8;
    if (i0 >= MK) return;
    const int k0 = i0 % K;
    const f32x4 a0 = *(const f32x4*)(x + i0);
    const f32x4 a1 = *(const f32x4*)(x + i0 + 4);
    const f32x4 s0 = *(const f32x4*)(smooth + k0);
    const f32x4 s1 = *(const f32x4*)(smooth + k0 + 4);
    f16x8 o;
#pragma unroll
    for (int j = 0; j < 4; ++j) {
        o[j]     = (f16)(a0[j] / s0[j]);
        o[j + 4] = (f16)(a1[j] / s1[j]);
    }
    *(f16x8*)(xs + i0) = o;
}

// ---------------------------------------------------------------------------
// Pre-pass 2: Bt[N,K] = fp16((q - zp) * scale)
// ---------------------------------------------------------------------------
__global__ __launch_bounds__(256) void dequant_kernel(
    const int* __restrict__ packed,    // [N, K/2]
    const float* __restrict__ wscale,  // [G, N]
    const float* __restrict__ wzero,   // [G, N]
    f16* __restrict__ Bt,              // [N, K]
    int N, int K)
{
    const int perrow = K >> 3;
    const int t = blockIdx.x * 256 + threadIdx.x;
    const int n = t / perrow;
    const int jt = t - n * perrow;
    if (n >= N) return;
    const int k0 = jt << 3;
    const int g = k0 >> 7;
    const int4v p = *(const int4v*)(packed + (size_t)n * (K >> 1) + (jt << 2));
    const float sc = wscale[(size_t)g * N + n];
    const float zp = wzero[(size_t)g * N + n];
    f16x8 o;
#pragma unroll
    for (int b = 0; b < 4; ++b) {
        const int byte = p[b];
        o[2 * b]     = (f16)(((float)((byte & 15) - 8) - zp) * sc);
        o[2 * b + 1] = (f16)(((float)(((byte >> 4) & 15) - 8) - zp) * sc);
    }
    *(f16x8*)(Bt + (size_t)n * K + k0) = o;
}

// ---------------------------------------------------------------------------
// GEMM: C = xs * Bt^T + bias (f32 out). 256x256 tile, BK=64, 8 waves (2x4),
// 4 phases/K-tile, ONE 8KB half-block staged pair per phase, counted vmcnt(2)
// only at ph1/ph4 (FIFO-derived race-free; never drains in-flight prefetch).
// Stage order B0,B1,Aj0,Aj1 -> B ages 3-5 phases (HBM), A 1-2 (L2-resident).
// r3-verified LDS layout + XOR chunk swizzle (0 conflicts), r7 supertile map
// (FETCH 0.43GB), r3 scatter epilogue (no spill), setprio on MFMA clusters.
// ---------------------------------------------------------------------------
__global__ __launch_bounds__(512, 2) void gemm_kernel(
    const f16* __restrict__ As,       // [M, K]
    const f16* __restrict__ Bt,       // [N, K]
    const float* __restrict__ bias,   // [N]
    float* __restrict__ C,            // [M, N]
    int M, int N, int K)
{
    __shared__ char lds[131072];

    const int t = threadIdx.x;
    const int lane = t & 63;
    const int wid = t >> 6;
    const int wr = wid >> 2;          // 0..1
    const int wc = wid & 3;           // 0..3
    const int fr = lane & 15;
    const int fq = lane >> 4;

    const int nbm = M / BM;           // 32
    const int nbn = N / BN;           // 43
    const int nwg = nbm * nbn;        // 1376
    const int bid = (int)blockIdx.x;

    int bm, bn;
    if (nbm == 32 && nbn == 43) {
        // r7-verified supertile map (FETCH 0.43 GB)
        const int x = bid & 7, s = bid >> 3;
        const int r = s >> 5, q = s & 31;
        const int pos = (r < 5) ? (r * 256 + x * 32 + q)
                                : (1280 + x * 12 + (s - 160));
        int st, w;
        if (pos < 1024)      { st = pos >> 8; w = pos & 255; }
        else if (pos < 1200) { st = 4;        w = pos - 1024; }
        else                 { st = 5;        w = pos - 1200; }
        if (st < 4) { bm = (st & 1) * 16 + (w >> 4); bn = (st >> 1) * 16 + (w & 15); }
        else        { bm = (st & 1) * 16 + (w / 11); bn = 32 + (w % 11); }
    } else {
        const int cpx = nwg >> 3;
        const int wg = (bid & 7) * cpx + (bid >> 3);
        bm = wg % nbm; bn = wg / nbm;
    }
    const size_t m0 = (size_t)bm * BM;
    const size_t n0 = (size_t)bn * BN;

    // ---- staging geometry (512 threads, one 8KB 64-row block per gload) ----
    const int rbase = t >> 3;                           // 0..63
    const int sck8 = (((t & 7) ^ ((t >> 3) & 7)) << 3); // swizzled chunk (f16)
    const f16* gAs = As + (m0 + rbase) * (size_t)K + sck8;
    const f16* gBs = Bt + (n0 + rbase) * (size_t)K + sck8;

#define STG_A(sb, blk, Tst) gload_lds16(gAs + (size_t)((blk) * 64) * K + (size_t)(Tst) * 64, \
                                        lds + (sb) + (blk) * 8192 + t * 16)
#define STG_B(sb, blk, Tst) gload_lds16(gBs + (size_t)((blk) * 64) * K + (size_t)(Tst) * 64, \
                                        lds + 65536 + (sb) + (blk) * 8192 + t * 16)

    // ---- ds_read lane constants (r3-verified, 0 bank conflicts) ----
    const int r7 = fr & 7;
    const int coff0 = ((fq ^ r7) << 4);
    const int coff1 = (((fq ^ r7) ^ 4) << 4);
    const int aBase = (wr << 14) + fr * 128;
    const int bBase = 65536 + ((wc >> 1) << 14) + ((wc & 1) << 13) + fr * 128;

#define LDA(db, m, kk) (*(const f16x8*)(lds + (db) + aBase + (m) * 2048 + ((kk) ? coff1 : coff0)))
#define LDB(db, n, kk) (*(const f16x8*)(lds + (db) + bBase + (n) * 2048 + ((kk) ? coff1 : coff0)))

    f32x4 acc[8][4];
#pragma unroll
    for (int m = 0; m < 8; ++m)
#pragma unroll
        for (int n = 0; n < 4; ++n)
            acc[m][n] = {0.f, 0.f, 0.f, 0.f};

    const int NT = K >> 6;            // 64 K-tiles

    // ---- prologue: stage all 8 blocks of tile 0 ----
#pragma unroll
    for (int blk = 0; blk < 4; ++blk) STG_A(0, blk, 0);
#pragma unroll
    for (int blk = 0; blk < 4; ++blk) STG_B(0, blk, 0);
    asm volatile("s_waitcnt vmcnt(0)" ::: "memory");
    __builtin_amdgcn_s_barrier();

#pragma unroll 1
    for (int T = 0; T < NT; ++T) {
        const int db = (T & 1) << 15;
        const int sb = ((T + 1) & 1) << 15;
        const bool st = (T + 1) < NT;
        f16x8 a03[8], a47[8], b01[4], b23[4];

        // ===== ph1: read a0-3 + b0-1; stage B blk0,1(T+1); vmcnt(2) =====
#pragma unroll
        for (int m = 0; m < 4; ++m) { a03[2*m] = LDA(db, m, 0); a03[2*m+1] = LDA(db, m, 1); }
#pragma unroll
        for (int n = 0; n < 2; ++n) { b01[2*n] = LDB(db, n, 0); b01[2*n+1] = LDB(db, n, 1); }
        if (st) { STG_B(sb, 0, T + 1); STG_B(sb, 1, T + 1); }
        if (st) { asm volatile("s_waitcnt vmcnt(2)" ::: "memory"); }
        else    { asm volatile("s_waitcnt vmcnt(0)" ::: "memory"); }
        __builtin_amdgcn_s_barrier();
        __builtin_amdgcn_s_setprio(1);
#pragma unroll
        for (int m = 0; m < 4; ++m)
#pragma unroll
            for (int n = 0; n < 2; ++n) {
                acc[m][n] = __builtin_amdgcn_mfma_f32_16x16x32_f16(a03[2*m],   b01[2*n],   acc[m][n], 0, 0, 0);
                acc[m][n] = __builtin_amdgcn_mfma_f32_16x16x32_f16(a03[2*m+1], b01[2*n+1], acc[m][n], 0, 0, 0);
            }
        __builtin_amdgcn_s_setprio(0);
        __builtin_amdgcn_s_barrier();

        // ===== ph2: read a4-7; stage B blk2,3(T+1) =====
#pragma unroll
        for (int m = 0; m < 4; ++m) { a47[2*m] = LDA(db, 4 + m, 0); a47[2*m+1] = LDA(db, 4 + m, 1); }
        if (st) { STG_B(sb, 2, T + 1); STG_B(sb, 3, T + 1); }
        __builtin_amdgcn_s_barrier();
        __builtin_amdgcn_s_setprio(1);
#pragma unroll
        for (int m = 0; m < 4; ++m)
#pragma unroll
            for (int n = 0; n < 2; ++n) {
                acc[4+m][n] = __builtin_amdgcn_mfma_f32_16x16x32_f16(a47[2*m],   b01[2*n],   acc[4+m][n], 0, 0, 0);
                acc[4+m][n] = __builtin_amdgcn_mfma_f32_16x16x32_f16(a47[2*m+1], b01[2*n+1], acc[4+m][n], 0, 0, 0);
            }
        __builtin_amdgcn_s_setprio(0);
        __builtin_amdgcn_s_barrier();

        // ===== ph3: read b2-3; stage A blk0,2 (j0 halves, T+1) =====
#pragma unroll
        for (int n = 0; n < 2; ++n) { b23[2*n] = LDB(db, 2 + n, 0); b23[2*n+1] = LDB(db, 2 + n, 1); }
        if (st) { STG_A(sb, 0, T + 1); STG_A(sb, 2, T + 1); }
        __builtin_amdgcn_s_barrier();
        __builtin_amdgcn_s_setprio(1);
#pragma unroll
        for (int m = 0; m < 4; ++m)
#pragma unroll
            for (int n = 0; n < 2; ++n) {
                acc[m][2+n] = __builtin_amdgcn_mfma_f32_16x16x32_f16(a03[2*m],   b23[2*n],   acc[m][2+n], 0, 0, 0);
                acc[m][2+n] = __builtin_amdgcn_mfma_f32_16x16x32_f16(a03[2*m+1], b23[2*n+1], acc[m][2+n], 0, 0, 0);
            }
        __builtin_amdgcn_s_setprio(0);
        __builtin_amdgcn_s_barrier();

        // ===== ph4: stage A blk1,3 (j1 halves, T+1); vmcnt(2) =====
        if (st) { STG_A(sb, 1, T + 1); STG_A(sb, 3, T + 1); }
        if (st) { asm volatile("s_waitcnt vmcnt(2)" ::: "memory"); }
        __builtin_amdgcn_s_barrier();
        __builtin_amdgcn_s_setprio(1);
#pragma unroll
        for (int m = 0; m < 4; ++m)
#pragma unroll
            for (int n = 0; n < 2; ++n) {
                acc[4+m][2+n] = __builtin_amdgcn_mfma_f32_16x16x32_f16(a47[2*m],   b23[2*n],   acc[4+m][2+n], 0, 0, 0);
                acc[4+m][2+n] = __builtin_amdgcn_mfma_f32_16x16x32_f16(a47[2*m+1], b23[2*n+1], acc[4+m][2+n], 0, 0, 0);
            }
        __builtin_amdgcn_s_setprio(0);
        __builtin_amdgcn_s_barrier();
    }

    // ---- epilogue: + bias, f32 scatter stores (static indices, no spill) ----
#pragma unroll
    for (int n = 0; n < 4; ++n) {
        const size_t gcol = n0 + wc * 64 + n * 16 + fr;
        const float bv = bias[gcol];
#pragma unroll
        for (int am = 0; am < 8; ++am) {
            const size_t grow = m0 + wr * 128 + am * 16 + fq * 4;
#pragma unroll
            for (int r = 0; r < 4; ++r)
                C[(grow + r) * N + gcol] = acc[am][n][r] + bv;
        }
    }
}

extern "C" void kernel_launch(void* const* d_in, const int* in_sizes, int n_in,
                              void* d_out, int out_size, void* d_ws, size_t ws_size,
                              hipStream_t stream) {
    const float* x      = (const float*)d_in[0];
    const int* packed   = (const int*)d_in[1];
    const float* wscale = (const float*)d_in[2];
    const float* wzero  = (const float*)d_in[3];
    const float* smooth = (const float*)d_in[4];
    const float* bias   = (const float*)d_in[5];
    float* out = (float*)d_out;

    const int K = in_sizes[4];             // 4096
    const int N = in_sizes[5];             // 11008
    const int M = in_sizes[0] / K;         // 8192
    const int MK = M * K;

    f16* xs = (f16*)d_ws;
    f16* Bt = (f16*)((char*)d_ws + (size_t)MK * sizeof(f16));

    smooth_kernel<<<(MK / 8 + 255) / 256, 256, 0, stream>>>(x, smooth, xs, MK, K);
    dequant_kernel<<<(N * (K >> 3) + 255) / 256, 256, 0, stream>>>(
        packed, wscale, wzero, Bt, N, K);

    const int grid_gemm = (M / BM) * (N / BN);
    gemm_kernel<<<grid_gemm, 512, 0, stream>>>(xs, Bt, bias, out, M, N, K);
}